// Round 4
// baseline (420.109 us; speedup 1.0000x reference)
//
#include <hip/hip_runtime.h>
#include <math.h>

#define GRID  512
#define BLK   512
#define NB    4
#define NITER 8      // 16384 / (GRID*NB)

typedef __attribute__((ext_vector_type(8))) short short8;
typedef __attribute__((ext_vector_type(4))) float f32x4;

__device__ __forceinline__ float sigf(float x) { return 1.0f / (1.0f + expf(-x)); }

__device__ __forceinline__ unsigned short f2bf(float x) {
    unsigned u = __float_as_uint(x);
    return (unsigned short)((u + 0x7fffu + ((u >> 16) & 1u)) >> 16);
}
__device__ __forceinline__ float bf2f(unsigned short h) {
    return __uint_as_float(((unsigned)h) << 16);
}
__device__ __forceinline__ unsigned short f2bf_trunc(float x) {
    return (unsigned short)(__float_as_uint(x) >> 16);
}

__device__ __forceinline__ void split8(const float4 p0, const float4 p1,
                                       short8& hi, short8& lo) {
    float xs[8] = {p0.x, p0.y, p0.z, p0.w, p1.x, p1.y, p1.z, p1.w};
#pragma unroll
    for (int i = 0; i < 8; ++i) {
        unsigned short h = f2bf(xs[i]);
        hi[i] = (short)h;
        lo[i] = (short)f2bf_trunc(xs[i] - bf2f(h));
    }
}

// M[k][j] such that q_flat = m_flat @ M reproduces the complex linear
__device__ __forceinline__ float Mmat(const float* __restrict__ wr,
                                      const float* __restrict__ wi, int k, int j) {
    if (j < 64) return (k < 64) ? wr[j * 64 + k] : -wi[j * 64 + (k - 64)];
    return (k < 64) ? wi[(j - 64) * 64 + k] : wr[(j - 64) * 64 + (k - 64)];
}

__global__ void prep_kernel(const float* __restrict__ wqr, const float* __restrict__ wqi,
                            const float* __restrict__ wkr, const float* __restrict__ wki,
                            const float* __restrict__ wvr, const float* __restrict__ wvi,
                            float* __restrict__ G, float* __restrict__ Mv,
                            int* __restrict__ cnt) {
    const int a = blockIdx.x;
    const int bb = threadIdx.x;
    if (a == 0 && bb == 0) *cnt = 0;
    float acc = 0.f;
    for (int j = 0; j < 128; ++j)
        acc += Mmat(wqr, wqi, a, j) * Mmat(wkr, wki, bb, j);
    G[a * 128 + bb] = 0.125f * acc;
    Mv[a * 128 + bb] = Mmat(wvr, wvi, a, bb);
}

// Pre-fragment G and Mv into MFMA B-operand layout, bf16 hi/lo planes.
__global__ void prep_frag(const float* __restrict__ G, const float* __restrict__ Mv,
                          unsigned short* __restrict__ Gf, unsigned short* __restrict__ Mvf) {
    const int bid = blockIdx.x;     // 64 = mat(2) * jt(8) * t(4)
    const int lane = threadIdx.x;   // 64
    const int mat = bid >> 5, jt = (bid >> 2) & 7, t = bid & 3;
    const float* X = mat ? Mv : G;
    unsigned short* O = mat ? Mvf : Gf;
    const int quad = lane >> 4, col = lane & 15;
    const int obase = ((jt * 4 + t) * 2) * 512 + lane * 8;
#pragma unroll
    for (int i = 0; i < 8; ++i) {
        int k = t * 32 + quad * 8 + i;
        int j = jt * 16 + col;
        float x = X[k * 128 + j];
        unsigned short h = f2bf(x);
        O[obase + i] = h;
        O[obase + 512 + i] = f2bf_trunc(x - bf2f(h));
    }
}

__global__ __launch_bounds__(BLK, 4) void crsn_main(
    const float* __restrict__ z_real, const float* __restrict__ z_imag,
    const float* __restrict__ mem, const float* __restrict__ ptr,
    const float* __restrict__ ctrl,
    const unsigned short* __restrict__ Gf, const unsigned short* __restrict__ Mvf,
    float* __restrict__ o_zr, float* __restrict__ o_zi,
    float* __restrict__ o_mem, float* __restrict__ o_np,
    int* __restrict__ g_cnt) {
    __shared__ __align__(16) float t1s[NB * 2112];               // 33792 B
    __shared__ __align__(16) unsigned short mfrag[NB * 8 * 520]; // 33280 B
    __shared__ float wl[NB][16];
    __shared__ int cnt_lds;

    const int tid = threadIdx.x;
    const int w = tid >> 6;       // wave 0..7: owns j-tile jt = w
    const int lane = tid & 63;
    const int quad = lane >> 4;
    const int col = lane & 15;
    const int snb = w >> 1;       // batch this wave blends
    const int half = w & 1;       // half of the batch row-block
    const int l31 = lane & 31;
    const int k0 = l31 << 2;                // blend column base (const across c)
    const int t0 = l31 >> 3;                // mfrag t for this lane
    const int q2 = (l31 >> 1) & 3;          // mfrag quad
    const int i0 = (lane & 1) << 2;         // mfrag sub-offset

    if (tid == 0) cnt_lds = 0;

    f32x4 acc1[NB], acc2[NB];

    // ---- prologue prefetch for it=0 ----
    const int base0 = blockIdx.x * (NB * NITER);
    f32x4 pm[4];
    f32x4 pz;
    float cb0, cb1, cb2;   // ctrl of blend batch
    float pva;             // ptr[s=lane&15] of attention batch
    float ca0, ca1, ca2;   // ctrl of attention batch
    {
        const int bs = base0 + snb;
        const f32x4* msrc = (const f32x4*)mem + (size_t)bs * 512 + half * 256 + lane;
#pragma unroll
        for (int c = 0; c < 4; ++c) pm[c] = __builtin_nontemporal_load(msrc + c * 64);
        pz = (l31 < 16) ? *(const f32x4*)(z_real + (bs << 6) + k0)
                        : *(const f32x4*)(z_imag + (bs << 6) + k0 - 64);
        cb0 = ctrl[bs * 3 + 0]; cb1 = ctrl[bs * 3 + 1]; cb2 = ctrl[bs * 3 + 2];
        const int b2 = base0 + (w & 3);
        pva = ptr[(b2 << 4) + col];
        ca0 = ctrl[b2 * 3 + 0]; ca1 = ctrl[b2 * 3 + 1]; ca2 = ctrl[b2 * 3 + 2];
    }

    for (int it = 0; it < NITER; ++it) {
        const int base = blockIdx.x * (NB * NITER) + it * NB;
        const int nbase = (it + 1 < NITER) ? base + NB : base;
        const int bs = base + snb;

        // ---- ph1: blend from prefetched regs -> o_mem (NT) + mfrag ----
        {
            float g0 = sigf(cb0), g1 = sigf(cb1), g2 = sigf(cb2);
            float push = g0 / (g0 + g1 + g2 + 1e-6f);
            float qq = 1.0f - push;
            f32x4* odst = (f32x4*)o_mem + (size_t)bs * 512 + half * 256 + lane;
#pragma unroll
            for (int c = 0; c < 4; ++c) {
                int su = half * 8 + c * 2 + (lane >> 5);
                f32x4 mn = pm[c] * qq + pz * push;
                __builtin_nontemporal_store(mn, odst + c * 64);
                int bidx = ((snb * 4 + t0) * 2) * 520 + (q2 * 16 + su) * 8 + i0;
                ushort4 hv, lv;
                hv.x = f2bf(mn[0]); hv.y = f2bf(mn[1]);
                hv.z = f2bf(mn[2]); hv.w = f2bf(mn[3]);
                lv.x = f2bf_trunc(mn[0] - bf2f(hv.x));
                lv.y = f2bf_trunc(mn[1] - bf2f(hv.y));
                lv.z = f2bf_trunc(mn[2] - bf2f(hv.z));
                lv.w = f2bf_trunc(mn[3] - bf2f(hv.w));
                *(ushort4*)&mfrag[bidx] = hv;
                *(ushort4*)&mfrag[bidx + 520] = lv;
            }
        }
        // ---- issue next-iter blend prefetch (overlaps ph2+ph3) ----
        {
            const int bs2 = nbase + snb;
            const f32x4* msrc = (const f32x4*)mem + (size_t)bs2 * 512 + half * 256 + lane;
#pragma unroll
            for (int c = 0; c < 4; ++c) pm[c] = __builtin_nontemporal_load(msrc + c * 64);
            pz = (l31 < 16) ? *(const f32x4*)(z_real + (bs2 << 6) + k0)
                            : *(const f32x4*)(z_imag + (bs2 << 6) + k0 - 64);
            cb0 = ctrl[bs2 * 3 + 0]; cb1 = ctrl[bs2 * 3 + 1]; cb2 = ctrl[bs2 * 3 + 2];
        }
        __syncthreads();  // B2: mfrag ready

        // ---- ph2: t1 = m@G, t2 = m@Mv via MFMA (hi/lo split); wave w = j-tile w ----
        {
#pragma unroll
            for (int nb = 0; nb < NB; ++nb) {
                acc1[nb] = (f32x4){0.f, 0.f, 0.f, 0.f};
                acc2[nb] = (f32x4){0.f, 0.f, 0.f, 0.f};
            }
#pragma unroll
            for (int t = 0; t < 4; ++t) {
                const unsigned short* fb = Gf + ((w * 4 + t) * 2) * 512 + lane * 8;
                const unsigned short* fb2 = Mvf + ((w * 4 + t) * 2) * 512 + lane * 8;
                short8 Gh = *(const short8*)fb;
                short8 Gl = *(const short8*)(fb + 512);
                short8 Mh = *(const short8*)fb2;
                short8 Ml = *(const short8*)(fb2 + 512);
#pragma unroll
                for (int nb = 0; nb < NB; ++nb) {
                    const unsigned short* mp = &mfrag[((nb * 4 + t) * 2) * 520 + lane * 8];
                    short8 ah = *(const short8*)mp;
                    short8 al = *(const short8*)(mp + 520);
                    acc1[nb] = __builtin_amdgcn_mfma_f32_16x16x32_bf16(ah, Gh, acc1[nb], 0, 0, 0);
                    acc1[nb] = __builtin_amdgcn_mfma_f32_16x16x32_bf16(ah, Gl, acc1[nb], 0, 0, 0);
                    acc1[nb] = __builtin_amdgcn_mfma_f32_16x16x32_bf16(al, Gh, acc1[nb], 0, 0, 0);
                    acc2[nb] = __builtin_amdgcn_mfma_f32_16x16x32_bf16(ah, Mh, acc2[nb], 0, 0, 0);
                    acc2[nb] = __builtin_amdgcn_mfma_f32_16x16x32_bf16(ah, Ml, acc2[nb], 0, 0, 0);
                    acc2[nb] = __builtin_amdgcn_mfma_f32_16x16x32_bf16(al, Mh, acc2[nb], 0, 0, 0);
                }
            }
#pragma unroll
            for (int nb = 0; nb < NB; ++nb)
#pragma unroll
                for (int reg = 0; reg < 4; ++reg)
                    t1s[nb * 2112 + (quad * 4 + reg) * 132 + w * 16 + col] = acc1[nb][reg];
        }
        __syncthreads();  // B3: t1 ready

        // ---- ph3a: waves 0..3: attention for batch base+w ----
        if (w < NB) {
            const int b2 = base + w;
            float h0 = sigf(ca0), h1 = sigf(ca1), h2 = sigf(ca2);
            float ht = h0 + h1 + h2 + 1e-6f;
            float pushb = h0 / ht, popb = h1 / ht, stayb = h2 / ht;

            float up = __shfl(pva, (lane + 15) & 15);
            float dn = __shfl(pva, (lane + 1) & 15);
            float npv = pushb * up + popb * dn + stayb * pva;
            if (lane < 16) o_np[(b2 << 4) + lane] = npv;
            unsigned long long bal = __ballot(lane < 16 && npv > 0.1f);
            if (lane == 0) atomicAdd(&cnt_lds, (int)__popcll(bal));

            f32x4 sc = (f32x4){0.f, 0.f, 0.f, 0.f};
#pragma unroll
            for (int t = 0; t < 4; ++t) {
                const float* tp = &t1s[w * 2112 + col * 132 + t * 32 + quad * 8];
                float4 p0 = *(const float4*)tp;
                float4 p1 = *(const float4*)(tp + 4);
                short8 ah, al;
                split8(p0, p1, ah, al);
                const unsigned short* mp = &mfrag[((w * 4 + t) * 2) * 520 + lane * 8];
                short8 bh = *(const short8*)mp;
                short8 bl = *(const short8*)(mp + 520);
                sc = __builtin_amdgcn_mfma_f32_16x16x32_bf16(ah, bh, sc, 0, 0, 0);
                sc = __builtin_amdgcn_mfma_f32_16x16x32_bf16(ah, bl, sc, 0, 0, 0);
                sc = __builtin_amdgcn_mfma_f32_16x16x32_bf16(al, bh, sc, 0, 0, 0);
            }
            float at[4];
#pragma unroll
            for (int reg = 0; reg < 4; ++reg) {
                float v = sc[reg];
                float mx = v;
                mx = fmaxf(mx, __shfl_xor(mx, 1));
                mx = fmaxf(mx, __shfl_xor(mx, 2));
                mx = fmaxf(mx, __shfl_xor(mx, 4));
                mx = fmaxf(mx, __shfl_xor(mx, 8));
                float e = expf(v - mx);
                float s2 = e;
                s2 += __shfl_xor(s2, 1);
                s2 += __shfl_xor(s2, 2);
                s2 += __shfl_xor(s2, 4);
                s2 += __shfl_xor(s2, 8);
                at[reg] = e / s2;
            }
            float wv = __shfl(npv, quad * 4 + 0) * at[0] + __shfl(npv, quad * 4 + 1) * at[1]
                     + __shfl(npv, quad * 4 + 2) * at[2] + __shfl(npv, quad * 4 + 3) * at[3];
            wv += __shfl_xor(wv, 16);
            wv += __shfl_xor(wv, 32);
            if (lane < 16) wl[w][lane] = wv;
        }
        // ---- issue next-iter attention prefetch (all waves) ----
        {
            const int b2n = nbase + (w & 3);
            pva = ptr[(b2n << 4) + col];
            ca0 = ctrl[b2n * 3 + 0]; ca1 = ctrl[b2n * 3 + 1]; ca2 = ctrl[b2n * 3 + 2];
        }
        __syncthreads();  // B4: wl ready; mfrag/t1s free for next iter

        // ---- ph3b: read[j] from live t2 C-frags; wave w covers j = w*16.. ----
#pragma unroll
        for (int nb = 0; nb < NB; ++nb) {
            float pr = wl[nb][quad * 4 + 0] * acc2[nb][0]
                     + wl[nb][quad * 4 + 1] * acc2[nb][1]
                     + wl[nb][quad * 4 + 2] * acc2[nb][2]
                     + wl[nb][quad * 4 + 3] * acc2[nb][3];
            pr += __shfl_xor(pr, 16);
            pr += __shfl_xor(pr, 32);
            if (lane < 16) {
                int j = (w << 4) + lane;
                int b2 = base + nb;
                if (j < 64) o_zr[(b2 << 6) + j] = pr;
                else        o_zi[(b2 << 6) + j - 64] = pr;
            }
        }
    }
    __syncthreads();
    if (tid == 0) atomicAdd(g_cnt, cnt_lds);
}

__global__ void fin_kernel(const int* __restrict__ cnt, float* __restrict__ o_act) {
    *o_act = (float)(*cnt) / 16384.0f;
}

extern "C" void kernel_launch(void* const* d_in, const int* in_sizes, int n_in,
                              void* d_out, int out_size, void* d_ws, size_t ws_size,
                              hipStream_t stream) {
    const float* z_real = (const float*)d_in[0];
    const float* z_imag = (const float*)d_in[1];
    const float* mem    = (const float*)d_in[2];
    const float* ptr    = (const float*)d_in[3];
    const float* ctrl   = (const float*)d_in[4];
    const float* wqr = (const float*)d_in[5];
    const float* wqi = (const float*)d_in[6];
    const float* wkr = (const float*)d_in[7];
    const float* wki = (const float*)d_in[8];
    const float* wvr = (const float*)d_in[9];
    const float* wvi = (const float*)d_in[10];

    float* out = (float*)d_out;
    float* o_zr  = out;
    float* o_zi  = out + 16384 * 64;
    float* o_mem = out + 2 * 16384 * 64;
    float* o_np  = o_mem + 16384 * 16 * 128;
    float* o_act = o_np + 16384 * 16;

    int*   cnt = (int*)d_ws;
    float* G   = (float*)((char*)d_ws + 256);
    float* Mv  = G + 128 * 128;
    unsigned short* Gfr  = (unsigned short*)(Mv + 128 * 128);
    unsigned short* Mvfr = Gfr + 32768;

    hipLaunchKernelGGL(prep_kernel, dim3(128), dim3(128), 0, stream,
                       wqr, wqi, wkr, wki, wvr, wvi, G, Mv, cnt);
    hipLaunchKernelGGL(prep_frag, dim3(64), dim3(64), 0, stream, G, Mv, Gfr, Mvfr);
    hipLaunchKernelGGL(crsn_main, dim3(GRID), dim3(BLK), 0, stream,
                       z_real, z_imag, mem, ptr, ctrl, Gfr, Mvfr,
                       o_zr, o_zi, o_mem, o_np, cnt);
    hipLaunchKernelGGL(fin_kernel, dim3(1), dim3(1), 0, stream, cnt, o_act);
}